// Round 6
// baseline (501.264 us; speedup 1.0000x reference)
//
#include <hip/hip_runtime.h>
#include <hip/hip_bf16.h>

namespace {

constexpr int NP   = 20000;   // points
constexpr int CD   = 384;     // channels
constexpr int QKVD = 1152;    // 3*C

typedef __attribute__((ext_vector_type(8))) short short8;
typedef __attribute__((ext_vector_type(4))) float f32x4;

// Correctly-rounded fp32 transcendentals via double (match reference libm).
__device__ inline float f32_atan2(float y, float x) {
  return (float)atan2((double)y, (double)x);
}
__device__ inline float f32_log(float x) {
  return (float)log((double)x);
}

__device__ inline float bfl(unsigned u) {   // low bf16 of dword -> f32
  union { unsigned u; float f; } c; c.u = u << 16; return c.f;
}
__device__ inline float bfh(unsigned u) {   // high bf16 of dword -> f32
  union { unsigned u; float f; } c; c.u = u & 0xffff0000u; return c.f;
}
__device__ inline float bfs(unsigned short v) {  // scalar bf16 -> f32
  union { unsigned u; float f; } c; c.u = ((unsigned)v) << 16; return c.f;
}
__device__ inline unsigned short f2bf(float x) {
  __hip_bfloat16 hb = __float2bfloat16(x);
  unsigned short u; __builtin_memcpy(&u, &hb, 2);
  return u;
}

// async 16B global -> LDS (global_load_lds_dwordx4). LDS dest must be the
// wave-uniform base; HW adds lane*16.
__device__ inline void async16(const void* g, void* l) {
  __builtin_amdgcn_global_load_lds(
      (const __attribute__((address_space(1))) unsigned int*)g,
      (__attribute__((address_space(3))) unsigned int*)l,
      16, 0, 0);
}

// ------------- fp32 -> bf16 elementwise (n divisible by 4) ------------------
__global__ __launch_bounds__(256) void cvt_bf16_k(const float* __restrict__ in,
                                                  unsigned short* __restrict__ out, int n) {
  int i = (blockIdx.x * 256 + threadIdx.x) * 4;
  if (i < n) {
    float4 v = *(const float4*)(in + i);
    ushort4 o;
    o.x = f2bf(v.x); o.y = f2bf(v.y); o.z = f2bf(v.z); o.w = f2bf(v.w);
    *(ushort4*)(out + i) = o;
  }
}

// ---- transpose + convert: in[R][Cc] fp32 -> out[Cc][R] bf16 ----------------
__global__ __launch_bounds__(256) void transpose_cvt_k(const float* __restrict__ in,
                                                       unsigned short* __restrict__ out,
                                                       int R, int Cc) {
  __shared__ float t[32][33];
  int c0 = blockIdx.x * 32, r0 = blockIdx.y * 32;
  int tx = threadIdx.x, ty = threadIdx.y;
  #pragma unroll
  for (int i = 0; i < 32; i += 8)
    t[ty + i][tx] = in[(size_t)(r0 + ty + i) * Cc + (c0 + tx)];
  __syncthreads();
  #pragma unroll
  for (int i = 0; i < 32; i += 8)
    out[(size_t)(c0 + ty + i) * R + (r0 + tx)] = f2bf(t[tx][ty + i]);
}

// ---- per-node spherical coords, fp32 op-order == reference ------------------
__global__ __launch_bounds__(256) void sphere_k(const float* __restrict__ xyz,
                                                float* __restrict__ sph) {
#pragma clang fp contract(off)
  int i = blockIdx.x * 256 + threadIdx.x;
  if (i < NP) {
    const float PIF = 3.14159265358979323846f;
    const float R2D = 57.29577951308232f;
    float x = xyz[i * 3 + 0], y = xyz[i * 3 + 1], z = xyz[i * 3 + 2];
    float sxy = x * x + y * y;
    sph[i * 3 + 0] = (f32_atan2(y, x) + PIF) * R2D;
    sph[i * 3 + 1] = f32_atan2(sqrtf(sxy), z) * R2D;
    sph[i * 3 + 2] = sqrtf(sxy + z * z);
  }
}

// ---------------- bf16 MFMA GEMM, async LDS staging (m97 structure) ---------
// C[M][Nn] = A[M][K] * BT[Nn][K]^T + bias.
// MODE 0: bf16 out, scale cols < 384 by 0.125 (q scaling). MODE 1: fp32 out.
// tile 128x128, BK=32, 4 waves (each 64x64), 16x16x32 bf16 MFMA.
// LDS unpadded [128][32]: global_load_lds writes wave-uniform base + lane*16.
template <int MODE>
__global__ __launch_bounds__(256) void gemm_async_k(const short* __restrict__ A,
                                                    const short* __restrict__ BT,
                                                    const float* __restrict__ bias,
                                                    void* __restrict__ Cout,
                                                    int M, int Nn, int K) {
  __shared__ short As[128][32];
  __shared__ short Bs[128][32];
  const int tid  = threadIdx.x;
  const int m0   = blockIdx.x * 128, n0 = blockIdx.y * 128;
  const int wave = tid >> 6, lane = tid & 63;
  const int wm   = (wave & 1) * 64, wn = (wave >> 1) * 64;
  const int quad = lane >> 4, l16 = lane & 15;
  // staging: one instruction covers 16 rows x 64B; lane -> (row=lane/4, 16B col=lane%4)
  const int srow = lane >> 2;
  const int scol = (lane & 3) * 8;   // shorts

  f32x4 acc[4][4] = {};

  for (int k0 = 0; k0 < K; k0 += 32) {
    #pragma unroll
    for (int c = 0; c < 2; ++c) {
      const int base = (wave + c * 4) * 16;      // wave-uniform: 0..112
      const int gmr = m0 + base + srow;
      if (gmr < M)
        async16(A + (size_t)gmr * K + k0 + scol, &As[base][0]);
      const int gnr = n0 + base + srow;
      if (gnr < Nn)
        async16(BT + (size_t)gnr * K + k0 + scol, &Bs[base][0]);
    }
    __syncthreads();   // drains vmcnt (global_load_lds) + lgkm
    short8 af[4], bg[4];
    #pragma unroll
    for (int i = 0; i < 4; ++i) af[i] = *(const short8*)&As[wm + i * 16 + l16][quad * 8];
    #pragma unroll
    for (int j = 0; j < 4; ++j) bg[j] = *(const short8*)&Bs[wn + j * 16 + l16][quad * 8];
    #pragma unroll
    for (int i = 0; i < 4; ++i)
      #pragma unroll
      for (int j = 0; j < 4; ++j)
        acc[i][j] = __builtin_amdgcn_mfma_f32_16x16x32_bf16(af[i], bg[j], acc[i][j], 0, 0, 0);
    __syncthreads();
  }

  #pragma unroll
  for (int i = 0; i < 4; ++i) {
    #pragma unroll
    for (int j = 0; j < 4; ++j) {
      int gn = n0 + wn + j * 16 + l16;
      if (gn >= Nn) continue;
      float bval = bias[gn];
      #pragma unroll
      for (int r = 0; r < 4; ++r) {
        int gm = m0 + wm + i * 16 + quad * 4 + r;
        if (gm < M) {
          float v = acc[i][j][r] + bval;
          if (MODE == 0) {
            if (gn < 384) v *= 0.125f;   // SCALE = 64^-0.5
            ((unsigned short*)Cout)[(size_t)gm * Nn + gn] = f2bf(v);
          } else {
            ((float*)Cout)[(size_t)gm * Nn + gn] = v;
          }
        }
      }
    }
  }
}

// 4 dims of the 7-dot logit: q,k are 2 packed-bf16 dwords; tables fp32.
__device__ inline void dot7_4(unsigned uq0, unsigned uq1, unsigned uk0, unsigned uk1,
                              float4 q0, float4 q1, float4 q2,
                              float4 k0, float4 k1, float4 k2,
                              float& aqk, float& aq0, float& aq1, float& aq2,
                              float& ak0, float& ak1, float& ak2) {
  float qa = bfl(uq0), qb = bfh(uq0), qc = bfl(uq1), qd = bfh(uq1);
  float ka = bfl(uk0), kb = bfh(uk0), kc = bfl(uk1), kd = bfh(uk1);
  aqk += qa * ka   + qb * kb   + qc * kc   + qd * kd;
  aq0 += qa * q0.x + qb * q0.y + qc * q0.z + qd * q0.w;
  aq1 += qa * q1.x + qb * q1.y + qc * q1.z + qd * q1.w;
  aq2 += qa * q2.x + qb * q2.y + qc * q2.z + qd * q2.w;
  ak0 += ka * k0.x + kb * k0.y + kc * k0.z + kd * k0.w;
  ak1 += ka * k1.x + kb * k1.y + kc * k1.z + kd * k1.w;
  ak2 += ka * k2.x + kb * k2.y + kc * k2.z + kd * k2.w;
}

// ---------------- fused sparse attention: 1 wave per (node, branch) ----------
// qkv: [N][1152] bf16 (q pre-scaled). Tables fp32 (L2-resident). xout bf16.
// All LDS wave-private -> no __syncthreads (same-wave DS ordering).
__global__ __launch_bounds__(256) void attn4_k(const unsigned short* __restrict__ qkv,
                                               const float* __restrict__ xyz,
                                               const float* __restrict__ sph,
                                               const int* __restrict__ nb_c,
                                               const int* __restrict__ nb_s,
                                               const float* __restrict__ tq_c,
                                               const float* __restrict__ tk_c,
                                               const float* __restrict__ tv_c,
                                               const float* __restrict__ tq_s,
                                               const float* __restrict__ tk_s,
                                               const float* __restrict__ tv_s,
                                               unsigned short* __restrict__ xout) {
  __shared__ int   s_i1 [4][16];
  __shared__ int   s_off[4][16][3];   // (idx*3+dim)*192 element offsets
  __shared__ float s_attn[4][3][16];
  __shared__ float s_p   [4][3][16];

  const int w    = threadIdx.x >> 6;
  const int lane = threadIdx.x & 63;
  const int n    = blockIdx.x * 2 + (w >> 1);   // grid = NP/2
  const int b    = w & 1;                       // branch: 0 cart, 1 sphere

  const float* tqb = b ? tq_s : tq_c;
  const float* tkb = b ? tk_s : tk_c;
  const float* tvb = b ? tv_s : tv_c;

  // ---- phase 0: neighbor indices + table-row offsets (bit-exact binning) ---
  if (lane < 16) {
#pragma clang fp contract(off)
    const int e = lane;
    if (b == 0) {
      const int i1 = nb_c[n * 16 + e];
      s_i1[w][e] = i1;
      const float rel[3] = {xyz[n * 3 + 0] - xyz[i1 * 3 + 0],
                            xyz[n * 3 + 1] - xyz[i1 * 3 + 1],
                            xyz[n * 3 + 2] - xyz[i1 * 3 + 2]};
      #pragma unroll
      for (int dim = 0; dim < 3; ++dim) {
        int idx = (int)floorf(rel[dim] * 4.0f) + 23;
        idx = min(max(idx, 0), 46);
        s_off[w][e][dim] = (idx * 3 + dim) * 192;
      }
    } else {
      const int i1 = nb_s[n * 16 + e];
      s_i1[w][e] = i1;
      const float d0 = sph[n * 3 + 0] - sph[i1 * 3 + 0];
      const float d1 = sph[n * 3 + 1] - sph[i1 * 3 + 1];
      const float dr = sph[n * 3 + 2] - sph[i1 * 3 + 2];
      int i0a = (int)floorf(d0 / 5.0f) + 24;
      int i1a = (int)floorf(d1 / 5.0f) + 24;
      const float ra = fabsf(dr);
      const float flag = (dr >= 0.0f) ? 1.0f : 0.0f;
      const float t = (ra + 0.025f) / 0.0125f;
      const float wv = f32_log(t) / 0.69314718055994531f;
      float fidx = 2.0f * floorf(wv) - 2.0f;
      fidx += ((3.0f * exp2f(floorf(fidx * 0.5f)) - 2.0f) * 0.0125f <= ra) ? 1.0f : 0.0f;
      fidx = fidx * (2.0f * flag - 1.0f) + (flag - 1.0f);
      int i2a = (int)fidx + 24;
      s_off[w][e][0] = (min(max(i0a, 0), 47) * 3 + 0) * 192;
      s_off[w][e][1] = (min(max(i1a, 0), 47) * 3 + 1) * 192;
      s_off[w][e][2] = (min(max(i2a, 0), 47) * 3 + 2) * 192;
    }
  }

  // ---- logits: lane = (edge, 16-dim group); 7 independent dot streams ----
  const int eg = lane >> 2, g = lane & 3;
  const int goff = g * 16;
  {
    const int i1 = s_i1[w][eg];
    const int o0 = s_off[w][eg][0];
    const int o1 = s_off[w][eg][1];
    const int o2 = s_off[w][eg][2];
    const unsigned short* kp = qkv + (size_t)i1 * QKVD + 384 + b * 192 + goff;
    const unsigned short* qp = qkv + (size_t)n * QKVD + b * 192 + goff;
    #pragma unroll
    for (int hh = 0; hh < 3; ++hh) {
      const int ho = hh * 64;
      const float* tA0 = tqb + o0 + ho + goff;
      const float* tA1 = tqb + o1 + ho + goff;
      const float* tA2 = tqb + o2 + ho + goff;
      const float* tB0 = tkb + o0 + ho + goff;
      const float* tB1 = tkb + o1 + ho + goff;
      const float* tB2 = tkb + o2 + ho + goff;
      uint4 qv0 = *(const uint4*)(qp + ho);
      uint4 qv1 = *(const uint4*)(qp + ho + 8);
      uint4 kv0 = *(const uint4*)(kp + ho);
      uint4 kv1 = *(const uint4*)(kp + ho + 8);
      const unsigned uq[8] = {qv0.x, qv0.y, qv0.z, qv0.w, qv1.x, qv1.y, qv1.z, qv1.w};
      const unsigned uk[8] = {kv0.x, kv0.y, kv0.z, kv0.w, kv1.x, kv1.y, kv1.z, kv1.w};
      float aqk = 0, aq0 = 0, aq1 = 0, aq2 = 0, ak0 = 0, ak1 = 0, ak2 = 0;
      #pragma unroll
      for (int j = 0; j < 4; ++j) {
        float4 A0 = *(const float4*)(tA0 + 4 * j);
        float4 A1 = *(const float4*)(tA1 + 4 * j);
        float4 A2 = *(const float4*)(tA2 + 4 * j);
        float4 B0 = *(const float4*)(tB0 + 4 * j);
        float4 B1 = *(const float4*)(tB1 + 4 * j);
        float4 B2 = *(const float4*)(tB2 + 4 * j);
        dot7_4(uq[2 * j], uq[2 * j + 1], uk[2 * j], uk[2 * j + 1],
               A0, A1, A2, B0, B1, B2, aqk, aq0, aq1, aq2, ak0, ak1, ak2);
      }
      float val = ((aqk + aq0) + (aq1 + aq2)) + ((ak0 + ak1) + ak2);
      val += __shfl_xor(val, 1);
      val += __shfl_xor(val, 2);
      if (g == 0) s_attn[w][hh][eg] = val;
    }
  }

  // ---- softmax over 16 edges per head (lanes 0..47) ----
  if (lane < 48) {
    const int hh = lane >> 4, ee = lane & 15;
    float a = s_attn[w][hh][ee];
    float m = a;
    #pragma unroll
    for (int off = 8; off > 0; off >>= 1) m = fmaxf(m, __shfl_xor(m, off));
    float ex = __expf(a - m);
    float s = ex;
    #pragma unroll
    for (int off = 8; off > 0; off >>= 1) s += __shfl_xor(s, off);
    s_p[w][hh][ee] = ex / s;
  }

  // ---- weighted V accumulate: lane = dim; Tv fp32 (no unpack) ----
  {
    float vacc[3] = {0.0f, 0.0f, 0.0f};
    for (int e2 = 0; e2 < 16; ++e2) {
      const int j1 = s_i1[w][e2];
      const int p0 = s_off[w][e2][0];
      const int p1 = s_off[w][e2][1];
      const int p2 = s_off[w][e2][2];
      const float pr0 = s_p[w][0][e2];
      const float pr1 = s_p[w][1][e2];
      const float pr2 = s_p[w][2][e2];
      const unsigned short* vp = qkv + (size_t)j1 * QKVD + 768 + b * 192 + lane;
      #pragma unroll
      for (int hh = 0; hh < 3; ++hh) {
        const int ho = hh * 64;
        float vd  = bfs(vp[ho]);
        float tvs = tvb[p0 + ho + lane] + tvb[p1 + ho + lane] + tvb[p2 + ho + lane];
        float pr = (hh == 0) ? pr0 : ((hh == 1) ? pr1 : pr2);
        vacc[hh] += pr * (vd + tvs);
      }
    }
    #pragma unroll
    for (int hh = 0; hh < 3; ++hh)
      xout[(size_t)n * CD + (b * 3 + hh) * 64 + lane] = f2bf(vacc[hh]);
  }
}

}  // namespace

extern "C" void kernel_launch(void* const* d_in, const int* in_sizes, int n_in,
                              void* d_out, int out_size, void* d_ws, size_t ws_size,
                              hipStream_t stream) {
  const float* qf    = (const float*)d_in[0];
  const float* xyz   = (const float*)d_in[1];
  const int*   i1c   = (const int*)d_in[3];   // index_1
  const int*   i1s   = (const int*)d_in[5];   // index_1_sphere
  const float* Wqkv  = (const float*)d_in[6];
  const float* bqkv  = (const float*)d_in[7];
  const float* Wproj = (const float*)d_in[8];
  const float* bproj = (const float*)d_in[9];
  const float* tq    = (const float*)d_in[10];
  const float* tk    = (const float*)d_in[11];
  const float* tv    = (const float*)d_in[12];
  const float* tqs   = (const float*)d_in[13];
  const float* tks   = (const float*)d_in[14];
  const float* tvs   = (const float*)d_in[15];

  char* w = (char*)d_ws;
  unsigned short* qf_b   = (unsigned short*)w; w += (size_t)NP * CD * 2;    // 15.36 MB
  unsigned short* wqkvT  = (unsigned short*)w; w += (size_t)QKVD * CD * 2;  // 0.88 MB
  unsigned short* wprojT = (unsigned short*)w; w += (size_t)CD * CD * 2;    // 0.29 MB
  unsigned short* qkv_b  = (unsigned short*)w; w += (size_t)NP * QKVD * 2;  // 46.08 MB
  unsigned short* x_b    = (unsigned short*)w; w += (size_t)NP * CD * 2;    // 15.36 MB
  float*          sph    = (float*)w;                                        // 0.24 MB

  cvt_bf16_k<<<(NP * CD / 4 + 255) / 256, 256, 0, stream>>>(qf, qf_b, NP * CD);
  transpose_cvt_k<<<dim3(QKVD / 32, CD / 32), dim3(32, 8), 0, stream>>>(Wqkv, wqkvT, CD, QKVD);
  transpose_cvt_k<<<dim3(CD / 32, CD / 32), dim3(32, 8), 0, stream>>>(Wproj, wprojT, CD, CD);
  sphere_k<<<(NP + 255) / 256, 256, 0, stream>>>(xyz, sph);

  gemm_async_k<0><<<dim3((NP + 127) / 128, QKVD / 128), 256, 0, stream>>>(
      (const short*)qf_b, (const short*)wqkvT, bqkv, qkv_b, NP, QKVD, CD);

  attn4_k<<<NP / 2, 256, 0, stream>>>(qkv_b, xyz, sph, i1c, i1s,
                                      tq, tk, tv, tqs, tks, tvs, x_b);

  gemm_async_k<1><<<dim3((NP + 127) / 128, CD / 128), 256, 0, stream>>>(
      (const short*)x_b, (const short*)wprojT, bproj, d_out, NP, CD, CD);
}

// Round 8
// 338.690 us; speedup vs baseline: 1.4800x; 1.4800x over previous
//
#include <hip/hip_runtime.h>
#include <hip/hip_bf16.h>

namespace {

constexpr int NP   = 20000;   // points
constexpr int CD   = 384;     // channels
constexpr int QKVD = 1152;    // 3*C
constexpr int TC   = 47 * 3 * 3 * 64;   // 27072 cart-table elems
constexpr int TS   = 48 * 3 * 3 * 64;   // 27648 sphere-table elems

typedef __attribute__((ext_vector_type(8))) short short8;
typedef __attribute__((ext_vector_type(4))) float f32x4;

// Correctly-rounded fp32 transcendentals via double (match reference libm).
__device__ inline float f32_atan2(float y, float x) {
  return (float)atan2((double)y, (double)x);
}
__device__ inline float f32_log(float x) {
  return (float)log((double)x);
}

__device__ inline float bfl(unsigned u) {   // low bf16 of dword -> f32
  union { unsigned u; float f; } c; c.u = u << 16; return c.f;
}
__device__ inline float bfh(unsigned u) {   // high bf16 of dword -> f32
  union { unsigned u; float f; } c; c.u = u & 0xffff0000u; return c.f;
}
__device__ inline float bfs(unsigned short v) {  // scalar bf16 -> f32
  union { unsigned u; float f; } c; c.u = ((unsigned)v) << 16; return c.f;
}
__device__ inline unsigned short f2bf(float x) {
  __hip_bfloat16 hb = __float2bfloat16(x);
  unsigned short u; __builtin_memcpy(&u, &hb, 2);
  return u;
}

// async 16B global -> LDS (global_load_lds_dwordx4). LDS dest must be the
// wave-uniform base; HW adds lane*16.
__device__ inline void async16(const void* g, void* l) {
  __builtin_amdgcn_global_load_lds(
      (const __attribute__((address_space(1))) unsigned int*)g,
      (__attribute__((address_space(3))) unsigned int*)l,
      16, 0, 0);
}

// ------------- fp32 -> bf16 elementwise (n divisible by 4) ------------------
__global__ __launch_bounds__(256) void cvt_bf16_k(const float* __restrict__ in,
                                                  unsigned short* __restrict__ out, int n) {
  int i = (blockIdx.x * 256 + threadIdx.x) * 4;
  if (i < n) {
    float4 v = *(const float4*)(in + i);
    ushort4 o;
    o.x = f2bf(v.x); o.y = f2bf(v.y); o.z = f2bf(v.z); o.w = f2bf(v.w);
    *(ushort4*)(out + i) = o;
  }
}

// ---- transpose + convert: in[R][Cc] fp32 -> out[Cc][R] bf16 ----------------
__global__ __launch_bounds__(256) void transpose_cvt_k(const float* __restrict__ in,
                                                       unsigned short* __restrict__ out,
                                                       int R, int Cc) {
  __shared__ float t[32][33];
  int c0 = blockIdx.x * 32, r0 = blockIdx.y * 32;
  int tx = threadIdx.x, ty = threadIdx.y;
  #pragma unroll
  for (int i = 0; i < 32; i += 8)
    t[ty + i][tx] = in[(size_t)(r0 + ty + i) * Cc + (c0 + tx)];
  __syncthreads();
  #pragma unroll
  for (int i = 0; i < 32; i += 8)
    out[(size_t)(c0 + ty + i) * R + (r0 + tx)] = f2bf(t[tx][ty + i]);
}

// ---- fused prep: 6 table converts (y=0..5) + spherical coords (y=6) --------
__global__ __launch_bounds__(256) void prep_k(const float* __restrict__ tq,
                                              const float* __restrict__ tk,
                                              const float* __restrict__ tv,
                                              const float* __restrict__ tqs,
                                              const float* __restrict__ tks,
                                              const float* __restrict__ tvs,
                                              unsigned short* __restrict__ tq_b,
                                              unsigned short* __restrict__ tk_b,
                                              unsigned short* __restrict__ tv_b,
                                              unsigned short* __restrict__ tqs_b,
                                              unsigned short* __restrict__ tks_b,
                                              unsigned short* __restrict__ tvs_b,
                                              const float* __restrict__ xyz,
                                              float* __restrict__ sph) {
  const int y = blockIdx.y;
  const int t = blockIdx.x * 256 + threadIdx.x;
  if (y < 6) {
    const float* in = (y == 0) ? tq : (y == 1) ? tk : (y == 2) ? tv
                    : (y == 3) ? tqs : (y == 4) ? tks : tvs;
    unsigned short* out = (y == 0) ? tq_b : (y == 1) ? tk_b : (y == 2) ? tv_b
                        : (y == 3) ? tqs_b : (y == 4) ? tks_b : tvs_b;
    const int n = (y < 3) ? TC : TS;   // both divisible by 4
    int i = t * 4;
    if (i < n) {
      float4 v = *(const float4*)(in + i);
      ushort4 o;
      o.x = f2bf(v.x); o.y = f2bf(v.y); o.z = f2bf(v.z); o.w = f2bf(v.w);
      *(ushort4*)(out + i) = o;
    }
  } else {
#pragma clang fp contract(off)
    #pragma unroll
    for (int r = 0; r < 4; ++r) {
      int i = t * 4 + r;
      if (i < NP) {
        const float PIF = 3.14159265358979323846f;
        const float R2D = 57.29577951308232f;
        float x = xyz[i * 3 + 0], yy = xyz[i * 3 + 1], z = xyz[i * 3 + 2];
        float sxy = x * x + yy * yy;
        sph[i * 3 + 0] = (f32_atan2(yy, x) + PIF) * R2D;
        sph[i * 3 + 1] = f32_atan2(sqrtf(sxy), z) * R2D;
        sph[i * 3 + 2] = sqrtf(sxy + z * z);
      }
    }
  }
}

// ---------------- bf16 MFMA GEMM, async LDS staging (m97 structure) ---------
// C[M][Nn] = A[M][K] * BT[Nn][K]^T + bias.
// MODE 0: bf16 out, scale cols < 384 by 0.125 (q scaling). MODE 1: fp32 out.
template <int MODE>
__global__ __launch_bounds__(256) void gemm_async_k(const short* __restrict__ A,
                                                    const short* __restrict__ BT,
                                                    const float* __restrict__ bias,
                                                    void* __restrict__ Cout,
                                                    int M, int Nn, int K) {
  __shared__ short As[128][32];
  __shared__ short Bs[128][32];
  const int tid  = threadIdx.x;
  const int m0   = blockIdx.x * 128, n0 = blockIdx.y * 128;
  const int wave = tid >> 6, lane = tid & 63;
  const int wm   = (wave & 1) * 64, wn = (wave >> 1) * 64;
  const int quad = lane >> 4, l16 = lane & 15;
  const int srow = lane >> 2;
  const int scol = (lane & 3) * 8;   // shorts

  f32x4 acc[4][4] = {};

  for (int k0 = 0; k0 < K; k0 += 32) {
    #pragma unroll
    for (int c = 0; c < 2; ++c) {
      const int base = (wave + c * 4) * 16;      // wave-uniform: 0..112
      const int gmr = m0 + base + srow;
      if (gmr < M)
        async16(A + (size_t)gmr * K + k0 + scol, &As[base][0]);
      const int gnr = n0 + base + srow;
      if (gnr < Nn)
        async16(BT + (size_t)gnr * K + k0 + scol, &Bs[base][0]);
    }
    __syncthreads();   // drains vmcnt (global_load_lds) + lgkm
    short8 af[4], bg[4];
    #pragma unroll
    for (int i = 0; i < 4; ++i) af[i] = *(const short8*)&As[wm + i * 16 + l16][quad * 8];
    #pragma unroll
    for (int j = 0; j < 4; ++j) bg[j] = *(const short8*)&Bs[wn + j * 16 + l16][quad * 8];
    #pragma unroll
    for (int i = 0; i < 4; ++i)
      #pragma unroll
      for (int j = 0; j < 4; ++j)
        acc[i][j] = __builtin_amdgcn_mfma_f32_16x16x32_bf16(af[i], bg[j], acc[i][j], 0, 0, 0);
    __syncthreads();
  }

  #pragma unroll
  for (int i = 0; i < 4; ++i) {
    #pragma unroll
    for (int j = 0; j < 4; ++j) {
      int gn = n0 + wn + j * 16 + l16;
      if (gn >= Nn) continue;
      float bval = bias[gn];
      #pragma unroll
      for (int r = 0; r < 4; ++r) {
        int gm = m0 + wm + i * 16 + quad * 4 + r;
        if (gm < M) {
          float v = acc[i][j][r] + bval;
          if (MODE == 0) {
            if (gn < 384) v *= 0.125f;   // SCALE = 64^-0.5
            ((unsigned short*)Cout)[(size_t)gm * Nn + gn] = f2bf(v);
          } else {
            ((float*)Cout)[(size_t)gm * Nn + gn] = v;
          }
        }
      }
    }
  }
}

// 8-dim partial: acc += q*(k+tq0+tq1+tq2) + k*(tk0+tk1+tk2), all bf16 dwords
__device__ inline float dot8(uint4 q, uint4 k, uint4 a0, uint4 a1, uint4 a2,
                             uint4 t0, uint4 t1, uint4 t2, float acc) {
  const unsigned* qp = &q.x;  const unsigned* kp = &k.x;
  const unsigned* a0p = &a0.x; const unsigned* a1p = &a1.x; const unsigned* a2p = &a2.x;
  const unsigned* t0p = &t0.x; const unsigned* t1p = &t1.x; const unsigned* t2p = &t2.x;
  #pragma unroll
  for (int w = 0; w < 4; ++w) {
    {
      float qf = bfl(qp[w]), kf = bfl(kp[w]);
      float tqs = bfl(a0p[w]) + bfl(a1p[w]) + bfl(a2p[w]);
      float tks = bfl(t0p[w]) + bfl(t1p[w]) + bfl(t2p[w]);
      acc += qf * (kf + tqs) + kf * tks;
    }
    {
      float qf = bfh(qp[w]), kf = bfh(kp[w]);
      float tqs = bfh(a0p[w]) + bfh(a1p[w]) + bfh(a2p[w]);
      float tks = bfh(t0p[w]) + bfh(t1p[w]) + bfh(t2p[w]);
      acc += qf * (kf + tqs) + kf * tks;
    }
  }
  return acc;
}

// ---------------- fused sparse attention: 1 wave per (node, branch) ----------
// qkv: [N][1152] bf16 (q pre-scaled). Tables bf16. xout: [N][384] bf16.
// All LDS wave-private -> no __syncthreads (same-wave DS ordering).
__global__ __launch_bounds__(256) void attn3_k(const unsigned short* __restrict__ qkv,
                                               const float* __restrict__ xyz,
                                               const float* __restrict__ sph,
                                               const int* __restrict__ nb_c,
                                               const int* __restrict__ nb_s,
                                               const unsigned short* __restrict__ tq_c,
                                               const unsigned short* __restrict__ tk_c,
                                               const unsigned short* __restrict__ tv_c,
                                               const unsigned short* __restrict__ tq_s,
                                               const unsigned short* __restrict__ tk_s,
                                               const unsigned short* __restrict__ tv_s,
                                               unsigned short* __restrict__ xout) {
  __shared__ int   s_i1 [4][16];
  __shared__ int   s_off[4][16][3];   // (idx*3+dim)*192 element offsets
  __shared__ float s_attn[4][3][16];
  __shared__ float s_p   [4][3][16];

  const int w    = threadIdx.x >> 6;
  const int lane = threadIdx.x & 63;
  const int n    = blockIdx.x * 2 + (w >> 1);   // grid = NP/2
  const int b    = w & 1;                       // branch: 0 cart, 1 sphere

  const unsigned short* tqb = b ? tq_s : tq_c;
  const unsigned short* tkb = b ? tk_s : tk_c;
  const unsigned short* tvb = b ? tv_s : tv_c;

  // ---- phase 0: neighbor indices + table-row offsets (bit-exact binning) ---
  if (lane < 16) {
#pragma clang fp contract(off)
    const int e = lane;
    if (b == 0) {
      const int i1 = nb_c[n * 16 + e];
      s_i1[w][e] = i1;
      const float rel[3] = {xyz[n * 3 + 0] - xyz[i1 * 3 + 0],
                            xyz[n * 3 + 1] - xyz[i1 * 3 + 1],
                            xyz[n * 3 + 2] - xyz[i1 * 3 + 2]};
      #pragma unroll
      for (int dim = 0; dim < 3; ++dim) {
        int idx = (int)floorf(rel[dim] * 4.0f) + 23;
        idx = min(max(idx, 0), 46);
        s_off[w][e][dim] = (idx * 3 + dim) * 192;
      }
    } else {
      const int i1 = nb_s[n * 16 + e];
      s_i1[w][e] = i1;
      const float d0 = sph[n * 3 + 0] - sph[i1 * 3 + 0];
      const float d1 = sph[n * 3 + 1] - sph[i1 * 3 + 1];
      const float dr = sph[n * 3 + 2] - sph[i1 * 3 + 2];
      int i0a = (int)floorf(d0 / 5.0f) + 24;
      int i1a = (int)floorf(d1 / 5.0f) + 24;
      const float ra = fabsf(dr);
      const float flag = (dr >= 0.0f) ? 1.0f : 0.0f;
      const float t = (ra + 0.025f) / 0.0125f;
      const float wv = f32_log(t) / 0.69314718055994531f;
      float fidx = 2.0f * floorf(wv) - 2.0f;
      fidx += ((3.0f * exp2f(floorf(fidx * 0.5f)) - 2.0f) * 0.0125f <= ra) ? 1.0f : 0.0f;
      fidx = fidx * (2.0f * flag - 1.0f) + (flag - 1.0f);
      int i2a = (int)fidx + 24;
      s_off[w][e][0] = (min(max(i0a, 0), 47) * 3 + 0) * 192;
      s_off[w][e][1] = (min(max(i1a, 0), 47) * 3 + 1) * 192;
      s_off[w][e][2] = (min(max(i2a, 0), 47) * 3 + 2) * 192;
    }
  }

  // ---- logits: lane = (edge, 16-dim group) ----
  const int eg = lane >> 2, g = lane & 3;
  const int goff = g * 16;
  {
    const int i1 = s_i1[w][eg];
    const int o0 = s_off[w][eg][0];
    const int o1 = s_off[w][eg][1];
    const int o2 = s_off[w][eg][2];
    const unsigned short* kp = qkv + (size_t)i1 * QKVD + 384 + b * 192 + goff;
    const unsigned short* qp = qkv + (size_t)n * QKVD + b * 192 + goff;
    #pragma unroll
    for (int hh = 0; hh < 3; ++hh) {
      const int ho = hh * 64;
      uint4 kv0 = *(const uint4*)(kp + ho);
      uint4 kv1 = *(const uint4*)(kp + ho + 8);
      uint4 qv0 = *(const uint4*)(qp + ho);
      uint4 qv1 = *(const uint4*)(qp + ho + 8);
      uint4 a00 = *(const uint4*)(tqb + o0 + ho + goff);
      uint4 a01 = *(const uint4*)(tqb + o0 + ho + goff + 8);
      uint4 a10 = *(const uint4*)(tqb + o1 + ho + goff);
      uint4 a11 = *(const uint4*)(tqb + o1 + ho + goff + 8);
      uint4 a20 = *(const uint4*)(tqb + o2 + ho + goff);
      uint4 a21 = *(const uint4*)(tqb + o2 + ho + goff + 8);
      uint4 b00 = *(const uint4*)(tkb + o0 + ho + goff);
      uint4 b01 = *(const uint4*)(tkb + o0 + ho + goff + 8);
      uint4 b10 = *(const uint4*)(tkb + o1 + ho + goff);
      uint4 b11 = *(const uint4*)(tkb + o1 + ho + goff + 8);
      uint4 b20 = *(const uint4*)(tkb + o2 + ho + goff);
      uint4 b21 = *(const uint4*)(tkb + o2 + ho + goff + 8);
      float acc = 0.0f;
      acc = dot8(qv0, kv0, a00, a10, a20, b00, b10, b20, acc);
      acc = dot8(qv1, kv1, a01, a11, a21, b01, b11, b21, acc);
      acc += __shfl_xor(acc, 1);
      acc += __shfl_xor(acc, 2);
      if (g == 0) s_attn[w][hh][eg] = acc;
    }
  }

  // ---- softmax over 16 edges per head (lanes 0..47) ----
  if (lane < 48) {
    const int hh = lane >> 4, ee = lane & 15;
    float a = s_attn[w][hh][ee];
    float m = a;
    #pragma unroll
    for (int off = 8; off > 0; off >>= 1) m = fmaxf(m, __shfl_xor(m, off));
    float ex = __expf(a - m);
    float s = ex;
    #pragma unroll
    for (int off = 8; off > 0; off >>= 1) s += __shfl_xor(s, off);
    s_p[w][hh][ee] = ex / s;
  }

  // ---- weighted V accumulate: lane = dim ----
  {
    float vacc[3] = {0.0f, 0.0f, 0.0f};
    for (int e2 = 0; e2 < 16; ++e2) {
      const int j1 = s_i1[w][e2];
      const int p0 = s_off[w][e2][0];
      const int p1 = s_off[w][e2][1];
      const int p2 = s_off[w][e2][2];
      const float pr0 = s_p[w][0][e2];
      const float pr1 = s_p[w][1][e2];
      const float pr2 = s_p[w][2][e2];
      const unsigned short* vp = qkv + (size_t)j1 * QKVD + 768 + b * 192 + lane;
      #pragma unroll
      for (int hh = 0; hh < 3; ++hh) {
        const int ho = hh * 64;
        float vd  = bfs(vp[ho]);
        float tvs = bfs(tvb[p0 + ho + lane]) + bfs(tvb[p1 + ho + lane]) +
                    bfs(tvb[p2 + ho + lane]);
        float pr = (hh == 0) ? pr0 : ((hh == 1) ? pr1 : pr2);
        vacc[hh] += pr * (vd + tvs);
      }
    }
    #pragma unroll
    for (int hh = 0; hh < 3; ++hh)
      xout[(size_t)n * CD + (b * 3 + hh) * 64 + lane] = f2bf(vacc[hh]);
  }
}

}  // namespace

extern "C" void kernel_launch(void* const* d_in, const int* in_sizes, int n_in,
                              void* d_out, int out_size, void* d_ws, size_t ws_size,
                              hipStream_t stream) {
  const float* qf    = (const float*)d_in[0];
  const float* xyz   = (const float*)d_in[1];
  const int*   i1c   = (const int*)d_in[3];   // index_1
  const int*   i1s   = (const int*)d_in[5];   // index_1_sphere
  const float* Wqkv  = (const float*)d_in[6];
  const float* bqkv  = (const float*)d_in[7];
  const float* Wproj = (const float*)d_in[8];
  const float* bproj = (const float*)d_in[9];
  const float* tq    = (const float*)d_in[10];
  const float* tk    = (const float*)d_in[11];
  const float* tv    = (const float*)d_in[12];
  const float* tqs   = (const float*)d_in[13];
  const float* tks   = (const float*)d_in[14];
  const float* tvs   = (const float*)d_in[15];

  char* w = (char*)d_ws;
  unsigned short* qf_b   = (unsigned short*)w; w += (size_t)NP * CD * 2;    // 15.36 MB
  unsigned short* wqkvT  = (unsigned short*)w; w += (size_t)QKVD * CD * 2;  // 0.88 MB
  unsigned short* wprojT = (unsigned short*)w; w += (size_t)CD * CD * 2;    // 0.29 MB
  unsigned short* qkv_b  = (unsigned short*)w; w += (size_t)NP * QKVD * 2;  // 46.08 MB
  unsigned short* x_b    = (unsigned short*)w; w += (size_t)NP * CD * 2;    // 15.36 MB
  float*          sph    = (float*)w;          w += (size_t)NP * 3 * 4;     // 0.24 MB
  unsigned short* tq_b   = (unsigned short*)w; w += (size_t)TC * 2;
  unsigned short* tk_b   = (unsigned short*)w; w += (size_t)TC * 2;
  unsigned short* tv_b   = (unsigned short*)w; w += (size_t)TC * 2;
  unsigned short* tqs_b  = (unsigned short*)w; w += (size_t)TS * 2;
  unsigned short* tks_b  = (unsigned short*)w; w += (size_t)TS * 2;
  unsigned short* tvs_b  = (unsigned short*)w;

  cvt_bf16_k<<<(NP * CD / 4 + 255) / 256, 256, 0, stream>>>(qf, qf_b, NP * CD);
  transpose_cvt_k<<<dim3(QKVD / 32, CD / 32), dim3(32, 8), 0, stream>>>(Wqkv, wqkvT, CD, QKVD);
  transpose_cvt_k<<<dim3(CD / 32, CD / 32), dim3(32, 8), 0, stream>>>(Wproj, wprojT, CD, CD);
  prep_k<<<dim3(27, 7), 256, 0, stream>>>(tq, tk, tv, tqs, tks, tvs,
                                          tq_b, tk_b, tv_b, tqs_b, tks_b, tvs_b, xyz, sph);

  gemm_async_k<0><<<dim3((NP + 127) / 128, QKVD / 128), 256, 0, stream>>>(
      (const short*)qf_b, (const short*)wqkvT, bqkv, qkv_b, NP, QKVD, CD);

  attn3_k<<<NP / 2, 256, 0, stream>>>(qkv_b, xyz, sph, i1c, i1s,
                                      tq_b, tk_b, tv_b, tqs_b, tks_b, tvs_b, x_b);

  gemm_async_k<1><<<dim3((NP + 127) / 128, CD / 128), 256, 0, stream>>>(
      (const short*)x_b, (const short*)wprojT, bproj, d_out, NP, CD, CD);
}